// Round 1
// baseline (227.404 us; speedup 1.0000x reference)
//
#include <hip/hip_runtime.h>
#include <math.h>
#include <stddef.h>

#define NN    4096
#define BATCH 2
#define CD    64
#define KSEL  24
#define LCAP  2048

// ---------------- block reduce helpers (256 threads, 4 waves) ----------------
__device__ __forceinline__ float blk_sum_f(float v, float* buf) {
#pragma unroll
  for (int off = 32; off; off >>= 1) v += __shfl_down(v, off);
  __syncthreads();
  if ((threadIdx.x & 63) == 0) buf[threadIdx.x >> 6] = v;
  __syncthreads();
  return buf[0] + buf[1] + buf[2] + buf[3];
}
__device__ __forceinline__ float blk_max_f(float v, float* buf) {
#pragma unroll
  for (int off = 32; off; off >>= 1) v = fmaxf(v, __shfl_down(v, off));
  __syncthreads();
  if ((threadIdx.x & 63) == 0) buf[threadIdx.x >> 6] = v;
  __syncthreads();
  return fmaxf(fmaxf(buf[0], buf[1]), fmaxf(buf[2], buf[3]));
}
__device__ __forceinline__ int blk_sum_i(int v, int* buf) {
#pragma unroll
  for (int off = 32; off; off >>= 1) v += __shfl_down(v, off);
  __syncthreads();
  if ((threadIdx.x & 63) == 0) buf[threadIdx.x >> 6] = v;
  __syncthreads();
  return buf[0] + buf[1] + buf[2] + buf[3];
}

// ---------------- prep: transpose tgt_desc (B,C,N) -> (B,N,C) ----------------
__global__ __launch_bounds__(256)
void prep_transpose(const float* __restrict__ td, float* __restrict__ tdT) {
  __shared__ float tile[64][65];
  int blk = blockIdx.x;
  int b  = blk >> 6;            // NN/64 = 64 tiles per batch
  int j0 = (blk & 63) << 6;
  int jl = threadIdx.x & 63;
  int cq = threadIdx.x >> 6;    // 0..3
  const float* srcp = td + (size_t)b * CD * NN;
#pragma unroll
  for (int r2 = 0; r2 < 16; ++r2) {
    int c = r2 * 4 + cq;
    tile[c][jl] = srcp[(size_t)c * NN + j0 + jl];
  }
  __syncthreads();
  float* dstp = tdT + (size_t)b * NN * CD;
#pragma unroll
  for (int r2 = 0; r2 < 16; ++r2) {
    int j = r2 * 4 + cq;
    dstp[(size_t)(j0 + j) * CD + jl] = tile[jl][j];
  }
}

// ---------------- prep: lmt[b][j] = max(log softmax(tgt_mlogits)[...,0], -20) -
__global__ __launch_bounds__(256)
void prep_lmt(const float* __restrict__ tml, float* __restrict__ lmt) {
  int idx = blockIdx.x * 256 + threadIdx.x;
  if (idx >= BATCH * NN) return;
  int b = idx >> 12, j = idx & (NN - 1);
  float l0 = tml[(size_t)b * 2 * NN + j];
  float l1 = tml[(size_t)b * 2 * NN + NN + j];
  float x  = l1 - l0;
  float sp = fmaxf(x, 0.0f) + log1pf(expf(-fabsf(x)));  // softplus(l1-l0)
  lmt[idx] = fmaxf(-sp, -20.0f);                        // log(sigmoid(l0-l1))
}

// ---------------- main: one block (256 thr) per (b,i) row ----------------
__global__ __launch_bounds__(256)
void matcher_main(const float* __restrict__ sc, const float* __restrict__ tc,
                  const float* __restrict__ sd, const float* __restrict__ td,
                  const float* __restrict__ tdT, const float* __restrict__ lmtb,
                  const float* __restrict__ sml, const float* __restrict__ tml,
                  const float* __restrict__ su, const float* __restrict__ tu,
                  float* __restrict__ oexp, float* __restrict__ odisp,
                  float* __restrict__ oprob, float* __restrict__ oconf,
                  float* __restrict__ oent, float* __restrict__ osrc) {
  __shared__ float4 sdp4[CD / 4];
  __shared__ float  scv[3];
  __shared__ __align__(16) int hist[1024];
  __shared__ float  cand[128];
  __shared__ int    candn;
  __shared__ int    sBin, sBelow;
  __shared__ float  sD24;
  __shared__ float  fbuf[4];
  __shared__ int    ibuf[4];
  __shared__ int    jlist[LCAP];
  __shared__ float  vlist[LCAP];
  __shared__ int    lcount;

  const int tid = threadIdx.x;
  const int row = blockIdx.x;
  const int b   = row >> 12;
  const int i   = row & (NN - 1);

  if (tid < CD)           ((float*)sdp4)[tid] = sd[(size_t)b * CD * NN + (size_t)tid * NN + i];
  else if (tid < CD + 3)  scv[tid - CD] = sc[(size_t)b * 3 * NN + (size_t)(tid - CD) * NN + i];
  ((int4*)hist)[tid] = make_int4(0, 0, 0, 0);
  if (tid == 0) { candn = 0; lcount = 0; }
  __syncthreads();

  const float s0 = scv[0], s1 = scv[1], s2 = scv[2];
  const float ssq  = s0 * s0 + s1 * s1 + s2 * s2;
  const float su_i = su[(size_t)b * NN + i];

  const float4* tcx = (const float4*)(tc + (size_t)b * 3 * NN);
  const float4* tcy = (const float4*)(tc + (size_t)b * 3 * NN + NN);
  const float4* tcz = (const float4*)(tc + (size_t)b * 3 * NN + 2 * NN);

  // ---- phase 1: distances (thread t owns j = 4*(t+256k)+r), histogram keys --
  float dist[4][4];
#pragma unroll
  for (int k = 0; k < 4; ++k) {
    int g = tid + 256 * k;
    float4 X = tcx[g], Y = tcy[g], Z = tcz[g];
    float xx[4] = {X.x, X.y, X.z, X.w};
    float yy[4] = {Y.x, Y.y, Y.z, Y.w};
    float zz[4] = {Z.x, Z.y, Z.z, Z.w};
#pragma unroll
    for (int r = 0; r < 4; ++r) {
      float t0 = xx[r], t1 = yy[r], t2 = zz[r];
      float tsq = t0 * t0 + t1 * t1 + t2 * t2;
      float dot = s0 * t0 + s1 * t1 + s2 * t2;
      float d2  = ssq + tsq - 2.0f * dot;
      float d   = sqrtf(fmaxf(d2, 1e-12f));
      dist[k][r] = d;
      int key = (int)(d * 160.0f);
      key = key > 1023 ? 1023 : key;
      atomicAdd(&hist[key], 1);
    }
  }

  // ---- zero-fill probs row early (float4); scatter happens after barriers ---
  {
    float4* prow = (float4*)(oprob + (size_t)row * NN);
    float4 z4; z4.x = z4.y = z4.z = z4.w = 0.0f;
#pragma unroll
    for (int k = 0; k < 4; ++k) prow[tid + 256 * k] = z4;
  }
  __syncthreads();

  // ---- locate histogram bin containing 24th smallest (block prefix scan) ----
  {
    int4 h4 = ((int4*)hist)[tid];
    int loc = h4.x + h4.y + h4.z + h4.w;
    int pre = loc;
#pragma unroll
    for (int off = 1; off < 64; off <<= 1) {
      int q = __shfl_up(pre, off);
      if ((tid & 63) >= off) pre += q;
    }
    if ((tid & 63) == 63) ibuf[tid >> 6] = pre;
    __syncthreads();
    int wbase = 0;
#pragma unroll
    for (int w = 0; w < 4; ++w) wbase += (w < (tid >> 6)) ? ibuf[w] : 0;
    int below = wbase + pre - loc;
    int hh[4] = {h4.x, h4.y, h4.z, h4.w};
#pragma unroll
    for (int q = 0; q < 4; ++q) {
      if (below < KSEL && below + hh[q] >= KSEL) { sBin = 4 * tid + q; sBelow = below; }
      below += hh[q];
    }
    __syncthreads();
  }
  const int Bstar = sBin;
  const int cb    = sBelow;

  // ---- collect candidates in the boundary bin, exact-rank the (24-cb)-th ----
#pragma unroll
  for (int k = 0; k < 4; ++k)
#pragma unroll
    for (int r = 0; r < 4; ++r) {
      float d = dist[k][r];
      int key = (int)(d * 160.0f);
      key = key > 1023 ? 1023 : key;
      if (key == Bstar) {
        int idx = atomicAdd(&candn, 1);
        if (idx < 128) cand[idx] = d;
      }
    }
  __syncthreads();
  const int nc   = candn;
  const int Krem = KSEL - cb;
  if (nc <= 128) {
    if (tid < nc) {
      float v = cand[tid];
      int lt = 0, le = 0;
      for (int m = 0; m < nc; ++m) { float u = cand[m]; lt += (u < v); le += (u <= v); }
      if (lt < Krem && le >= Krem) sD24 = v;
    }
    __syncthreads();
  } else {
    // pathological bin: exact uint binary search over all 4096 distances
    unsigned lo = 0u, hi = 0x7F800000u;
    while (lo < hi) {
      unsigned mid = (lo + hi) >> 1;
      int c = 0;
#pragma unroll
      for (int k = 0; k < 4; ++k)
#pragma unroll
        for (int r = 0; r < 4; ++r) c += (__float_as_uint(dist[k][r]) <= mid);
      c = blk_sum_i(c, ibuf);
      if (c >= KSEL) hi = mid; else lo = mid + 1;
    }
    if (tid == 0) sD24 = __uint_as_float(lo);
    __syncthreads();
  }
  const float thresh = fmaxf(sD24, 0.45f);

  // ---- compact allowed entries into LDS list (j, dist) ----
#pragma unroll
  for (int k = 0; k < 4; ++k) {
    int g = tid + 256 * k;
#pragma unroll
    for (int r = 0; r < 4; ++r) {
      float d = dist[k][r];
      if (d <= thresh) {
        int idx = atomicAdd(&lcount, 1);
        if (idx < LCAP) { jlist[idx] = 4 * g + r; vlist[idx] = d; }
      }
    }
  }
  __syncthreads();
  const int na = lcount < LCAP ? lcount : LCAP;

  // ---- dense 64-dot scores for the allowed list ----
  for (int e = tid; e < na; e += 256) {
    int j  = jlist[e];
    float d = vlist[e];
    float sim = 0.0f;
    if (tdT) {
      const float4* trow = (const float4*)(tdT + ((size_t)b * NN + (size_t)j) * CD);
#pragma unroll
      for (int q = 0; q < CD / 4; ++q) {
        float4 a = sdp4[q], t4 = trow[q];
        sim = fmaf(a.x, t4.x, sim); sim = fmaf(a.y, t4.y, sim);
        sim = fmaf(a.z, t4.z, sim); sim = fmaf(a.w, t4.w, sim);
      }
    } else {
      const float* spx = (const float*)sdp4;
      const float* tp  = td + (size_t)b * CD * NN + j;
#pragma unroll 8
      for (int c = 0; c < CD; ++c) sim = fmaf(spx[c], tp[(size_t)c * NN], sim);
    }
    float lmtv;
    if (lmtb) {
      lmtv = lmtb[(size_t)b * NN + j];
    } else {
      float l0 = tml[(size_t)b * 2 * NN + j];
      float l1 = tml[(size_t)b * 2 * NN + NN + j];
      float x  = l1 - l0;
      float sp2 = fmaxf(x, 0.0f) + log1pf(expf(-fabsf(x)));
      lmtv = fmaxf(-sp2, -20.0f);
    }
    float tuj = tu[(size_t)b * NN + j];
    vlist[e] = sim - d - 0.1f * (su_i + tuj) + lmtv;   // score
  }

  // ---- online softmax over the list ----
  float mloc = -1e30f;
  for (int e = tid; e < na; e += 256) mloc = fmaxf(mloc, vlist[e]);
  float m = blk_max_f(mloc, fbuf);

  const float INVT = 1.0f / 0.07f;
  float zl = 0.0f;
  for (int e = tid; e < na; e += 256) {
    float ev = expf((vlist[e] - m) * INVT);
    vlist[e] = ev;
    zl += ev;
  }
  float Z = blk_sum_f(zl, fbuf);
  float invZ = 1.0f / Z;

  const float STEP = 2.0f / 15.0f;
  float ex0 = 0.f, ex1 = 0.f, ex2 = 0.f, entl = 0.f, pm = 0.f;
  for (int e = tid; e < na; e += 256) {
    float p = vlist[e] * invZ;
    int j = jlist[e];
    oprob[(size_t)row * NN + j] = p;   // zeros already laid down before barriers
    float pz = -1.0f + STEP * (float)(j >> 8);
    float py = -1.0f + STEP * (float)((j >> 4) & 15);
    float px = -1.0f + STEP * (float)(j & 15);
    ex0 += p * pz; ex1 += p * py; ex2 += p * px;
    if (p > 0.0f) { entl -= p * logf(fmaxf(p, 1e-12f)); pm = fmaxf(pm, p); }
  }
  ex0  = blk_sum_f(ex0, fbuf);
  ex1  = blk_sum_f(ex1, fbuf);
  ex2  = blk_sum_f(ex2, fbuf);
  entl = blk_sum_f(entl, fbuf);
  pm   = blk_max_f(pm, fbuf);

  if (tid == 0) {
    float tz = -1.0f + STEP * (float)(i >> 8);
    float ty = -1.0f + STEP * (float)((i >> 4) & 15);
    float tx = -1.0f + STEP * (float)(i & 15);
    size_t r3 = (size_t)row * 3;
    oexp[r3 + 0] = ex0; oexp[r3 + 1] = ex1; oexp[r3 + 2] = ex2;
    osrc[r3 + 0] = tz;  osrc[r3 + 1] = ty;  osrc[r3 + 2] = tx;
    size_t db = (size_t)b * 3 * NN;
    odisp[db + 0 * NN + i] = ex0 - tz;
    odisp[db + 1 * NN + i] = ex1 - ty;
    odisp[db + 2 * NN + i] = ex2 - tx;
    float ls0 = sml[(size_t)b * 2 * NN + i];
    float ls1 = sml[(size_t)b * 2 * NN + NN + i];
    float smv = 1.0f / (1.0f + expf(ls1 - ls0));  // softmax(src_mlogits)[...,0]
    oconf[(size_t)b * NN + i] = pm * smv;
    oent[(size_t)b * NN + i]  = entl;
  }
}

extern "C" void kernel_launch(void* const* d_in, const int* in_sizes, int n_in,
                              void* d_out, int out_size, void* d_ws, size_t ws_size,
                              hipStream_t stream) {
  const float* sc  = (const float*)d_in[0];
  const float* tc  = (const float*)d_in[1];
  const float* sd  = (const float*)d_in[2];
  const float* td  = (const float*)d_in[3];
  const float* sml = (const float*)d_in[4];
  const float* tml = (const float*)d_in[5];
  const float* su  = (const float*)d_in[6];
  const float* tu  = (const float*)d_in[7];

  float* out   = (float*)d_out;
  float* oexp  = out;
  float* odisp = oexp  + (size_t)BATCH * NN * 3;
  float* oprob = odisp + (size_t)BATCH * NN * 3;
  float* oconf = oprob + (size_t)BATCH * NN * NN;
  float* oent  = oconf + (size_t)BATCH * NN;
  float* osrc  = oent  + (size_t)BATCH * NN;

  size_t need = ((size_t)BATCH * NN * CD + (size_t)BATCH * NN) * sizeof(float);
  float* tdT = nullptr;
  float* lmt = nullptr;
  if (ws_size >= need) {
    tdT = (float*)d_ws;
    lmt = tdT + (size_t)BATCH * NN * CD;
    prep_transpose<<<BATCH * (NN / 64), 256, 0, stream>>>(td, tdT);
    prep_lmt<<<(BATCH * NN) / 256, 256, 0, stream>>>(tml, lmt);
  }
  matcher_main<<<BATCH * NN, 256, 0, stream>>>(sc, tc, sd, td, tdT, lmt, sml, tml,
                                               su, tu, oexp, odisp, oprob, oconf,
                                               oent, osrc);
}

// Round 2
// 221.409 us; speedup vs baseline: 1.0271x; 1.0271x over previous
//
#include <hip/hip_runtime.h>
#include <math.h>
#include <stddef.h>

#define NN    4096
#define BATCH 2
#define CD    64
#define KSEL  24
#define LCAP  1024
#define RAD2  0.2025f   // 0.45^2

// block int-sum (only used in the ~never-taken fallback path)
__device__ __forceinline__ int blk_sum_i(int v, int* buf) {
#pragma unroll
  for (int off = 32; off; off >>= 1) v += __shfl_down(v, off);
  __syncthreads();
  if ((threadIdx.x & 63) == 0) buf[threadIdx.x >> 6] = v;
  __syncthreads();
  return buf[0] + buf[1] + buf[2] + buf[3];
}

// ---- prep: transpose td & sd to (B,N,C); addj[b,j] = clamp(log tgt_match,-20) - 0.1*tu ----
__global__ __launch_bounds__(256)
void prep_all(const float* __restrict__ td, const float* __restrict__ sd,
              const float* __restrict__ tml, const float* __restrict__ tu,
              float* __restrict__ tdT, float* __restrict__ sdT,
              float* __restrict__ addj) {
  __shared__ float tile[64][65];
  int blk = blockIdx.x;
  if (blk < 256) {
    const float* src = (blk < 128) ? td  : sd;
    float*       dst = (blk < 128) ? tdT : sdT;
    int lb = blk & 127;
    int b  = lb >> 6;
    int j0 = (lb & 63) << 6;
    int jl = threadIdx.x & 63;
    int cq = threadIdx.x >> 6;
    const float* srcp = src + (size_t)b * CD * NN;
#pragma unroll
    for (int r = 0; r < 16; ++r) {
      int c = r * 4 + cq;
      tile[c][jl] = srcp[(size_t)c * NN + j0 + jl];
    }
    __syncthreads();
    float* dstp = dst + (size_t)b * NN * CD;
#pragma unroll
    for (int r = 0; r < 16; ++r) {
      int j = r * 4 + cq;
      dstp[(size_t)(j0 + j) * CD + jl] = tile[jl][j];
    }
  } else {
    int idx = (blk - 256) * 256 + threadIdx.x;   // 32 blocks cover B*N = 8192
    if (idx < BATCH * NN) {
      int b = idx >> 12, j = idx & (NN - 1);
      float l0 = tml[(size_t)b * 2 * NN + j];
      float l1 = tml[(size_t)b * 2 * NN + NN + j];
      float x  = l1 - l0;
      float sp = fmaxf(x, 0.0f) + log1pf(expf(-fabsf(x)));  // softplus(l1-l0)
      addj[idx] = fmaxf(-sp, -20.0f) - 0.1f * tu[idx];
    }
  }
}

// ---- main: one block (256 thr) per (b,i) row ----
__global__ __launch_bounds__(256)
void matcher_main(const float* __restrict__ sc, const float* __restrict__ tc,
                  const float* __restrict__ sd, const float* __restrict__ td,
                  const float* __restrict__ tdT, const float* __restrict__ sdT,
                  const float* __restrict__ addj,
                  const float* __restrict__ tml, const float* __restrict__ tu,
                  const float* __restrict__ sml,
                  float* __restrict__ oexp, float* __restrict__ odisp,
                  float* __restrict__ oprob, float* __restrict__ oconf,
                  float* __restrict__ oent, float* __restrict__ osrc) {
  __shared__ float4 sdp4[CD / 4];
  __shared__ float  scv[3];
  __shared__ __align__(16) int hist[1024];
  __shared__ float  cand[128];
  __shared__ int    candn;
  __shared__ int    sBin, sBelow;
  __shared__ float  sD24;          // 24th-smallest d^2
  __shared__ int    ibuf[4];
  __shared__ int    jlist[LCAP];
  __shared__ float  vlist[LCAP];
  __shared__ int    lcount;

  const int tid = threadIdx.x;
  const int row = blockIdx.x;
  const int b   = row >> 12;
  const int i   = row & (NN - 1);

  if (sdT) {
    if (tid < CD / 4) sdp4[tid] = ((const float4*)(sdT + ((size_t)b * NN + i) * CD))[tid];
  } else {
    if (tid < CD) ((float*)sdp4)[tid] = sd[(size_t)b * CD * NN + (size_t)tid * NN + i];
  }
  if (tid >= 64 && tid < 67) scv[tid - 64] = sc[(size_t)b * 3 * NN + (size_t)(tid - 64) * NN + i];
  ((int4*)hist)[tid] = make_int4(0, 0, 0, 0);
  if (tid == 0) { candn = 0; lcount = 0; sBin = -1; }
  __syncthreads();

  const float s0 = scv[0], s1 = scv[1], s2 = scv[2];
  const float ssq = s0 * s0 + s1 * s1 + s2 * s2;

  const float4* tcx = (const float4*)(tc + (size_t)b * 3 * NN);
  const float4* tcy = tcx + NN / 4;
  const float4* tcz = tcy + NN / 4;

  // ---- phase 1: squared distances; histogram only d2 < 1.0 (P ~= 8%) ----
  float d2v[4][4];
#pragma unroll
  for (int k = 0; k < 4; ++k) {
    int g = tid + 256 * k;
    float4 X = tcx[g], Y = tcy[g], Z = tcz[g];
    float xx[4] = {X.x, X.y, X.z, X.w};
    float yy[4] = {Y.x, Y.y, Y.z, Y.w};
    float zz[4] = {Z.x, Z.y, Z.z, Z.w};
#pragma unroll
    for (int r = 0; r < 4; ++r) {
      float t0 = xx[r], t1 = yy[r], t2 = zz[r];
      float tsq = t0 * t0 + t1 * t1 + t2 * t2;
      float dot = s0 * t0 + s1 * t1 + s2 * t2;
      float d2  = fmaxf(ssq + tsq - 2.0f * dot, 1e-12f);
      d2v[k][r] = d2;
      if (d2 < 1.0f) atomicAdd(&hist[(int)(d2 * 1024.0f)], 1);
    }
  }

  // ---- zero-fill probs row (overlaps with hist/scan) ----
  {
    float4* prow = (float4*)(oprob + (size_t)row * NN);
    float4 z4; z4.x = z4.y = z4.z = z4.w = 0.0f;
#pragma unroll
    for (int k = 0; k < 4; ++k) prow[tid + 256 * k] = z4;
  }
  __syncthreads();

  // ---- find bin containing 24th-smallest d2 (block prefix scan over 1024 bins) ----
  {
    int4 h4 = ((int4*)hist)[tid];
    int loc = h4.x + h4.y + h4.z + h4.w;
    int pre = loc;
#pragma unroll
    for (int off = 1; off < 64; off <<= 1) {
      int q = __shfl_up(pre, off);
      if ((tid & 63) >= off) pre += q;
    }
    if ((tid & 63) == 63) ibuf[tid >> 6] = pre;
    __syncthreads();
    int wbase = 0;
#pragma unroll
    for (int w = 0; w < 4; ++w) wbase += (w < (tid >> 6)) ? ibuf[w] : 0;
    int below = wbase + pre - loc;
    int hh[4] = {h4.x, h4.y, h4.z, h4.w};
#pragma unroll
    for (int q = 0; q < 4; ++q) {
      if (below < KSEL && below + hh[q] >= KSEL) { sBin = 4 * tid + q; sBelow = below; }
      below += hh[q];
    }
    __syncthreads();
  }
  const int Bstar = sBin;
  const int cb    = sBelow;
  bool fb = (Bstar < 0);   // <24 entries below d2=1.0 — essentially never

  if (!fb) {
#pragma unroll
    for (int k = 0; k < 4; ++k)
#pragma unroll
      for (int r = 0; r < 4; ++r) {
        float d2 = d2v[k][r];
        if (d2 < 1.0f && (int)(d2 * 1024.0f) == Bstar) {
          int idx = atomicAdd(&candn, 1);
          if (idx < 128) cand[idx] = d2;
        }
      }
    __syncthreads();
    if (candn > 128) fb = true;
  }
  if (!fb) {
    int nc = candn, Krem = KSEL - cb;
    if (tid < nc) {
      float v = cand[tid];
      int lt = 0, le = 0;
      for (int m2 = 0; m2 < nc; ++m2) { float u = cand[m2]; lt += (u < v); le += (u <= v); }
      if (lt < Krem && le >= Krem) sD24 = v;
    }
  } else {
    // exact uint binary search over all 4096 d2 values (uniform branch)
    unsigned lo = 0u, hi = 0x7F800000u;
    while (lo < hi) {
      unsigned mid = (lo + hi) >> 1;
      int c = 0;
#pragma unroll
      for (int k = 0; k < 4; ++k)
#pragma unroll
        for (int r = 0; r < 4; ++r) c += (__float_as_uint(d2v[k][r]) <= mid);
      c = blk_sum_i(c, ibuf);
      if (c >= KSEL) hi = mid; else lo = mid + 1;
    }
    if (tid == 0) sD24 = __uint_as_float(lo);
  }
  __syncthreads();
  const float thr2 = fmaxf(sD24, RAD2);

  // ---- compact allowed entries (j, d2) into LDS ----
#pragma unroll
  for (int k = 0; k < 4; ++k) {
    int g = tid + 256 * k;
#pragma unroll
    for (int r = 0; r < 4; ++r) {
      float d2 = d2v[k][r];
      if (d2 <= thr2) {
        int idx = atomicAdd(&lcount, 1);
        if (idx < LCAP) { jlist[idx] = 4 * g + r; vlist[idx] = d2; }
      }
    }
  }
  __syncthreads();               // LAST block-wide barrier
  const int na = lcount < LCAP ? lcount : LCAP;

  if (tid >= 64) return;         // waves 1..3 retire; wave 0 finishes the row

  // ---- wave-0 tail: scores -> online softmax -> outputs (shuffles only) ----
  const float* tdb = tdT ? tdT + (size_t)b * NN * CD : nullptr;
  float mloc = -1e30f;
  for (int e = tid; e < na; e += 64) {
    int j   = jlist[e];
    float d2 = vlist[e];
    float sim = 0.0f;
    if (tdb) {
      const float4* trow = (const float4*)(tdb + (size_t)j * CD);
#pragma unroll
      for (int q = 0; q < CD / 4; ++q) {
        float4 a = sdp4[q], t = trow[q];
        sim = fmaf(a.x, t.x, fmaf(a.y, t.y, fmaf(a.z, t.z, fmaf(a.w, t.w, sim))));
      }
    } else {
      const float* spx = (const float*)sdp4;
      const float* tp  = td + (size_t)b * CD * NN + j;
#pragma unroll 8
      for (int c = 0; c < CD; ++c) sim = fmaf(spx[c], tp[(size_t)c * NN], sim);
    }
    float aj;
    if (addj) {
      aj = addj[(size_t)b * NN + j];
    } else {
      float l0 = tml[(size_t)b * 2 * NN + j];
      float l1 = tml[(size_t)b * 2 * NN + NN + j];
      float x  = l1 - l0;
      float sp = fmaxf(x, 0.0f) + log1pf(expf(-fabsf(x)));
      aj = fmaxf(-sp, -20.0f) - 0.1f * tu[(size_t)b * NN + j];
    }
    float s = sim - sqrtf(d2) + aj;
    vlist[e] = s;
    mloc = fmaxf(mloc, s);
  }
#pragma unroll
  for (int off = 32; off; off >>= 1) mloc = fmaxf(mloc, __shfl_xor(mloc, off));
  const float m = mloc;

  const float C1 = (1.0f / 0.07f) * 1.44269504089f;  // log2(e)/TEMP
  float zl = 0.0f, evu = 0.0f, evm = 0.0f;
  for (int e = tid; e < na; e += 64) {
    float u  = (vlist[e] - m) * C1;
    float ev = exp2f(u);
    vlist[e] = ev;
    zl  += ev;
    evu  = fmaf(ev, u, evu);
    evm  = fmaxf(evm, ev);
  }
#pragma unroll
  for (int off = 32; off; off >>= 1) {
    zl  += __shfl_xor(zl, off);
    evu += __shfl_xor(evu, off);
    evm  = fmaxf(evm, __shfl_xor(evm, off));
  }
  const float Z = zl, invZ = 1.0f / zl;

  const float STEP = 2.0f / 15.0f;
  float ex0 = 0.f, ex1 = 0.f, ex2 = 0.f;
  for (int e = tid; e < na; e += 64) {
    float p = vlist[e] * invZ;
    int j = jlist[e];
    oprob[(size_t)row * NN + j] = p;
    float pz = -1.0f + STEP * (float)(j >> 8);
    float py = -1.0f + STEP * (float)((j >> 4) & 15);
    float px = -1.0f + STEP * (float)(j & 15);
    ex0 = fmaf(p, pz, ex0); ex1 = fmaf(p, py, ex1); ex2 = fmaf(p, px, ex2);
  }
#pragma unroll
  for (int off = 32; off; off >>= 1) {
    ex0 += __shfl_xor(ex0, off);
    ex1 += __shfl_xor(ex1, off);
    ex2 += __shfl_xor(ex2, off);
  }

  if (tid == 0) {
    const float LN2 = 0.69314718056f;
    float ent = LN2 * (log2f(Z) - evu * invZ);       // = lnZ - sum p*ln(ev)
    float tz = -1.0f + STEP * (float)(i >> 8);
    float ty = -1.0f + STEP * (float)((i >> 4) & 15);
    float tx = -1.0f + STEP * (float)(i & 15);
    size_t r3 = (size_t)row * 3;
    oexp[r3 + 0] = ex0; oexp[r3 + 1] = ex1; oexp[r3 + 2] = ex2;
    osrc[r3 + 0] = tz;  osrc[r3 + 1] = ty;  osrc[r3 + 2] = tx;
    size_t db = (size_t)b * 3 * NN;
    odisp[db + 0 * NN + i] = ex0 - tz;
    odisp[db + 1 * NN + i] = ex1 - ty;
    odisp[db + 2 * NN + i] = ex2 - tx;
    float ls0 = sml[(size_t)b * 2 * NN + i];
    float ls1 = sml[(size_t)b * 2 * NN + NN + i];
    float smv = 1.0f / (1.0f + expf(ls1 - ls0));     // softmax(src_mlogits)[...,0]
    oconf[(size_t)b * NN + i] = (evm * invZ) * smv;
    oent[(size_t)b * NN + i]  = ent;
  }
}

extern "C" void kernel_launch(void* const* d_in, const int* in_sizes, int n_in,
                              void* d_out, int out_size, void* d_ws, size_t ws_size,
                              hipStream_t stream) {
  const float* sc  = (const float*)d_in[0];
  const float* tc  = (const float*)d_in[1];
  const float* sd  = (const float*)d_in[2];
  const float* td  = (const float*)d_in[3];
  const float* sml = (const float*)d_in[4];
  const float* tml = (const float*)d_in[5];
  const float* tu  = (const float*)d_in[7];
  // src_unc (d_in[6]) cancels in the row-softmax -> unused

  float* out   = (float*)d_out;
  float* oexp  = out;
  float* odisp = oexp  + (size_t)BATCH * NN * 3;
  float* oprob = odisp + (size_t)BATCH * NN * 3;
  float* oconf = oprob + (size_t)BATCH * NN * NN;
  float* oent  = oconf + (size_t)BATCH * NN;
  float* osrc  = oent  + (size_t)BATCH * NN;

  size_t need = ((size_t)2 * BATCH * NN * CD + (size_t)BATCH * NN) * sizeof(float);
  float* tdT = nullptr;
  float* sdT = nullptr;
  float* adj = nullptr;
  if (ws_size >= need) {
    tdT = (float*)d_ws;
    sdT = tdT + (size_t)BATCH * NN * CD;
    adj = sdT + (size_t)BATCH * NN * CD;
    prep_all<<<256 + 32, 256, 0, stream>>>(td, sd, tml, tu, tdT, sdT, adj);
  }
  matcher_main<<<BATCH * NN, 256, 0, stream>>>(sc, tc, sd, td, tdT, sdT, adj,
                                               tml, tu, sml,
                                               oexp, odisp, oprob, oconf, oent, osrc);
}

// Round 3
// 206.949 us; speedup vs baseline: 1.0988x; 1.0699x over previous
//
#include <hip/hip_runtime.h>
#include <math.h>
#include <stddef.h>

#define NN    4096
#define BATCH 2
#define CD    64
#define KSEL  24
#define RAD2  0.2025f     // 0.45^2
#define NBINS 256
#define KBASE 1888        // (118<<4): d2 in [2^-9, 2^7) keyed by float bits>>19
#define CCAP  128
#define LCAP  256

__device__ __forceinline__ int d2key(float d2) {
  int k = (int)(__float_as_uint(d2) >> 19) - KBASE;
  return k < 0 ? 0 : (k > NBINS - 1 ? NBINS - 1 : k);
}

// ---- prep: transpose td & sd to (B,N,C); addj = clamp(log tgt_match,-20) - 0.1*tu ----
__global__ __launch_bounds__(256)
void prep_all(const float* __restrict__ td, const float* __restrict__ sd,
              const float* __restrict__ tml, const float* __restrict__ tu,
              float* __restrict__ tdT, float* __restrict__ sdT,
              float* __restrict__ addj) {
  __shared__ float tile[64][65];
  int blk = blockIdx.x;
  if (blk < 256) {
    const float* src = (blk < 128) ? td  : sd;
    float*       dst = (blk < 128) ? tdT : sdT;
    int lb = blk & 127;
    int b  = lb >> 6;
    int j0 = (lb & 63) << 6;
    int jl = threadIdx.x & 63;
    int cq = threadIdx.x >> 6;
    const float* srcp = src + (size_t)b * CD * NN;
#pragma unroll
    for (int r = 0; r < 16; ++r) {
      int c = r * 4 + cq;
      tile[c][jl] = srcp[(size_t)c * NN + j0 + jl];
    }
    __syncthreads();
    float* dstp = dst + (size_t)b * NN * CD;
#pragma unroll
    for (int r = 0; r < 16; ++r) {
      int j = r * 4 + cq;
      dstp[(size_t)(j0 + j) * CD + jl] = tile[jl][j];
    }
  } else {
    int idx = (blk - 256) * 256 + threadIdx.x;
    if (idx < BATCH * NN) {
      int b = idx >> 12, j = idx & (NN - 1);
      float l0 = tml[(size_t)b * 2 * NN + j];
      float l1 = tml[(size_t)b * 2 * NN + NN + j];
      float x  = l1 - l0;
      float sp = fmaxf(x, 0.0f) + log1pf(expf(-fabsf(x)));
      addj[idx] = fmaxf(-sp, -20.0f) - 0.1f * tu[idx];
    }
  }
}

// ---- main: one WAVE per row; 4 rows per block; no __syncthreads ----
__global__ __launch_bounds__(256, 6)
void matcher_main(const float* __restrict__ sc, const float* __restrict__ tc,
                  const float* __restrict__ sd, const float* __restrict__ td,
                  const float* __restrict__ tdT, const float* __restrict__ sdT,
                  const float* __restrict__ addj,
                  const float* __restrict__ tml, const float* __restrict__ tu,
                  const float* __restrict__ sml,
                  float* __restrict__ oexp, float* __restrict__ odisp,
                  float* __restrict__ oprob, float* __restrict__ oconf,
                  float* __restrict__ oent, float* __restrict__ osrc) {
  __shared__ __align__(16) int   hist[4][NBINS];
  __shared__ __align__(16) float sdp[4][CD];
  __shared__ float cand_d[4][CCAP];
  __shared__ int   cand_j[4][CCAP];
  __shared__ int   jlist[4][LCAP];
  __shared__ float vlist[4][LCAP];
  __shared__ int   candn[4], lcount[4];
  __shared__ float sD24[4];

  const int tid  = threadIdx.x;
  const int w    = tid >> 6;
  const int lane = tid & 63;
  const int row  = blockIdx.x * 4 + w;
  const int b    = row >> 12;
  const int i    = row & (NN - 1);

  // per-wave init
  ((int4*)hist[w])[lane] = make_int4(0, 0, 0, 0);
  if (lane == 0) { candn[w] = 0; lcount[w] = 0; }
  if (sdT) sdp[w][lane] = sdT[((size_t)b * NN + i) * CD + lane];
  else     sdp[w][lane] = sd[(size_t)b * CD * NN + (size_t)lane * NN + i];
  const float s0 = sc[(size_t)b * 3 * NN + i];
  const float s1 = sc[(size_t)b * 3 * NN + NN + i];
  const float s2 = sc[(size_t)b * 3 * NN + 2 * NN + i];
  __threadfence_block();

  const float4* tcx = (const float4*)(tc + (size_t)b * 3 * NN);
  const float4* tcy = tcx + NN / 4;
  const float4* tcz = tcy + NN / 4;
  float4* prow4 = (float4*)(oprob + (size_t)row * NN);
  float4 z4; z4.x = z4.y = z4.z = z4.w = 0.0f;

  // ---- pass A: histogram all 4096 d2 (log bins); interleave probs zero-fill ----
#pragma unroll 4
  for (int k = 0; k < 16; ++k) {
    int g = (k << 6) + lane;
    float4 X = tcx[g], Y = tcy[g], Z = tcz[g];
    prow4[g] = z4;
    float xs[4] = {X.x, X.y, X.z, X.w};
    float ys[4] = {Y.x, Y.y, Y.z, Y.w};
    float zs[4] = {Z.x, Z.y, Z.z, Z.w};
#pragma unroll
    for (int r = 0; r < 4; ++r) {
      float dx = xs[r] - s0, dy = ys[r] - s1, dz = zs[r] - s2;
      float d2 = fmaxf(__fmaf_rn(dx, dx, __fmaf_rn(dy, dy, dz * dz)), 1e-12f);
      atomicAdd(&hist[w][d2key(d2)], 1);
    }
  }
  __threadfence_block();

  // ---- wave scan of 256 bins -> bin holding 24th-smallest ----
  int4 h4 = ((int4*)hist[w])[lane];
  int hv[4] = {h4.x, h4.y, h4.z, h4.w};
  int s = hv[0] + hv[1] + hv[2] + hv[3];
  int inc = s;
#pragma unroll
  for (int off = 1; off < 64; off <<= 1) {
    int t = __shfl_up(inc, off);
    if (lane >= off) inc += t;
  }
  int pre = inc - s;               // exclusive prefix across lanes
  int Bl = -1, Bb = 0, below = pre;
#pragma unroll
  for (int q = 0; q < 4; ++q) {
    if (Bl < 0 && below < KSEL && below + hv[q] >= KSEL) { Bl = 4 * lane + q; Bb = below; }
    below += hv[q];
  }
  unsigned long long mk = __ballot(Bl >= 0);
  int srcl = __ffsll(mk) - 1;
  const int Bstar = __shfl(Bl, srcl);
  const int cb    = __shfl(Bb, srcl);
  const int Krem  = KSEL - cb;
  // default d24 = bin upper edge (overwritten by exact rank below)
  if (lane == 0) sD24[w] = __uint_as_float((unsigned)(Bstar + KBASE + 1) << 19);

  // ---- pass B: recompute d2 (bitwise-identical), classify ----
#pragma unroll 4
  for (int k = 0; k < 16; ++k) {
    int g = (k << 6) + lane;
    float4 X = tcx[g], Y = tcy[g], Z = tcz[g];
    float xs[4] = {X.x, X.y, X.z, X.w};
    float ys[4] = {Y.x, Y.y, Y.z, Y.w};
    float zs[4] = {Z.x, Z.y, Z.z, Z.w};
#pragma unroll
    for (int r = 0; r < 4; ++r) {
      float dx = xs[r] - s0, dy = ys[r] - s1, dz = zs[r] - s2;
      float d2 = fmaxf(__fmaf_rn(dx, dx, __fmaf_rn(dy, dy, dz * dz)), 1e-12f);
      int key = d2key(d2);
      int j = (g << 2) + r;
      if (key == Bstar) {
        int c = atomicAdd(&candn[w], 1);
        if (c < CCAP) { cand_d[w][c] = d2; cand_j[w][c] = j; }
      } else if (key < Bstar || d2 <= RAD2) {
        int c = atomicAdd(&lcount[w], 1);
        if (c < LCAP) { jlist[w][c] = j; vlist[w][c] = d2; }
      }
    }
  }
  __threadfence_block();

  // ---- exact rank inside boundary bin -> d24; append allowed candidates ----
  int nc = candn[w]; nc = nc > CCAP ? CCAP : nc;
  for (int e = lane; e < nc; e += 64) {
    float v = cand_d[w][e];
    int lt = 0, le = 0;
    for (int m = 0; m < nc; ++m) { float u = cand_d[w][m]; lt += (u < v); le += (u <= v); }
    if (lt < Krem && le >= Krem) sD24[w] = v;
  }
  __threadfence_block();
  const float thr2 = fmaxf(sD24[w], RAD2);
  for (int e = lane; e < nc; e += 64) {
    float v = cand_d[w][e];
    if (v <= thr2) {
      int c = atomicAdd(&lcount[w], 1);
      if (c < LCAP) { jlist[w][c] = cand_j[w][e]; vlist[w][c] = v; }
    }
  }
  __threadfence_block();
  int na = lcount[w]; na = na > LCAP ? LCAP : na;

  // ---- scores over allowed list ----
  const float* tdb = tdT ? tdT + (size_t)b * NN * CD : nullptr;
  const float4* sdp4 = (const float4*)sdp[w];
  float mloc = -1e30f;
  for (int e = lane; e < na; e += 64) {
    int j = jlist[w][e];
    float d2 = vlist[w][e];
    float sim = 0.0f;
    if (tdb) {
      const float4* trow = (const float4*)(tdb + (size_t)j * CD);
#pragma unroll
      for (int q = 0; q < CD / 4; ++q) {
        float4 a = sdp4[q], t = trow[q];
        sim = fmaf(a.x, t.x, fmaf(a.y, t.y, fmaf(a.z, t.z, fmaf(a.w, t.w, sim))));
      }
    } else {
      const float* spx = (const float*)sdp4;
      const float* tp  = td + (size_t)b * CD * NN + j;
#pragma unroll 8
      for (int c = 0; c < CD; ++c) sim = fmaf(spx[c], tp[(size_t)c * NN], sim);
    }
    float aj;
    if (addj) {
      aj = addj[(size_t)b * NN + j];
    } else {
      float l0 = tml[(size_t)b * 2 * NN + j];
      float l1 = tml[(size_t)b * 2 * NN + NN + j];
      float x  = l1 - l0;
      float sp = fmaxf(x, 0.0f) + log1pf(expf(-fabsf(x)));
      aj = fmaxf(-sp, -20.0f) - 0.1f * tu[(size_t)b * NN + j];
    }
    float sco = sim - sqrtf(d2) + aj;
    vlist[w][e] = sco;
    mloc = fmaxf(mloc, sco);
  }
#pragma unroll
  for (int off = 32; off; off >>= 1) mloc = fmaxf(mloc, __shfl_xor(mloc, off));
  const float m = mloc;

  const float C1 = (1.0f / 0.07f) * 1.44269504089f;   // log2(e)/TEMP
  float zl = 0.0f, evu = 0.0f, evm = 0.0f;
  for (int e = lane; e < na; e += 64) {
    float u  = (vlist[w][e] - m) * C1;
    float ev = exp2f(u);
    vlist[w][e] = ev;
    zl  += ev;
    evu  = fmaf(ev, u, evu);
    evm  = fmaxf(evm, ev);
  }
#pragma unroll
  for (int off = 32; off; off >>= 1) {
    zl  += __shfl_xor(zl, off);
    evu += __shfl_xor(evu, off);
    evm  = fmaxf(evm, __shfl_xor(evm, off));
  }
  const float Z = zl, invZ = 1.0f / zl;

  // drain zero-fill stores before scattering nonzeros into the same lines
  __builtin_amdgcn_s_waitcnt(0x0F70);   // vmcnt(0)

  const float STEP = 2.0f / 15.0f;
  float ex0 = 0.f, ex1 = 0.f, ex2 = 0.f;
  for (int e = lane; e < na; e += 64) {
    float p = vlist[w][e] * invZ;
    int j = jlist[w][e];
    oprob[(size_t)row * NN + j] = p;
    float pz = -1.0f + STEP * (float)(j >> 8);
    float py = -1.0f + STEP * (float)((j >> 4) & 15);
    float px = -1.0f + STEP * (float)(j & 15);
    ex0 = fmaf(p, pz, ex0); ex1 = fmaf(p, py, ex1); ex2 = fmaf(p, px, ex2);
  }
#pragma unroll
  for (int off = 32; off; off >>= 1) {
    ex0 += __shfl_xor(ex0, off);
    ex1 += __shfl_xor(ex1, off);
    ex2 += __shfl_xor(ex2, off);
  }

  if (lane == 0) {
    const float LN2 = 0.69314718056f;
    float ent = LN2 * (log2f(Z) - evu * invZ);
    float tz = -1.0f + STEP * (float)(i >> 8);
    float ty = -1.0f + STEP * (float)((i >> 4) & 15);
    float tx = -1.0f + STEP * (float)(i & 15);
    size_t r3 = (size_t)row * 3;
    oexp[r3 + 0] = ex0; oexp[r3 + 1] = ex1; oexp[r3 + 2] = ex2;
    osrc[r3 + 0] = tz;  osrc[r3 + 1] = ty;  osrc[r3 + 2] = tx;
    size_t db = (size_t)b * 3 * NN;
    odisp[db + 0 * NN + i] = ex0 - tz;
    odisp[db + 1 * NN + i] = ex1 - ty;
    odisp[db + 2 * NN + i] = ex2 - tx;
    float ls0 = sml[(size_t)b * 2 * NN + i];
    float ls1 = sml[(size_t)b * 2 * NN + NN + i];
    float smv = 1.0f / (1.0f + expf(ls1 - ls0));
    oconf[(size_t)b * NN + i] = (evm * invZ) * smv;
    oent[(size_t)b * NN + i]  = ent;
  }
}

extern "C" void kernel_launch(void* const* d_in, const int* in_sizes, int n_in,
                              void* d_out, int out_size, void* d_ws, size_t ws_size,
                              hipStream_t stream) {
  const float* sc  = (const float*)d_in[0];
  const float* tc  = (const float*)d_in[1];
  const float* sd  = (const float*)d_in[2];
  const float* td  = (const float*)d_in[3];
  const float* sml = (const float*)d_in[4];
  const float* tml = (const float*)d_in[5];
  const float* tu  = (const float*)d_in[7];
  // src_unc (d_in[6]) cancels in the row softmax -> unused

  float* out   = (float*)d_out;
  float* oexp  = out;
  float* odisp = oexp  + (size_t)BATCH * NN * 3;
  float* oprob = odisp + (size_t)BATCH * NN * 3;
  float* oconf = oprob + (size_t)BATCH * NN * NN;
  float* oent  = oconf + (size_t)BATCH * NN;
  float* osrc  = oent  + (size_t)BATCH * NN;

  size_t need = ((size_t)2 * BATCH * NN * CD + (size_t)BATCH * NN) * sizeof(float);
  float* tdT = nullptr;
  float* sdT = nullptr;
  float* adj = nullptr;
  if (ws_size >= need) {
    tdT = (float*)d_ws;
    sdT = tdT + (size_t)BATCH * NN * CD;
    adj = sdT + (size_t)BATCH * NN * CD;
    prep_all<<<256 + 32, 256, 0, stream>>>(td, sd, tml, tu, tdT, sdT, adj);
  }
  matcher_main<<<BATCH * NN / 4, 256, 0, stream>>>(sc, tc, sd, td, tdT, sdT, adj,
                                                   tml, tu, sml,
                                                   oexp, odisp, oprob, oconf, oent, osrc);
}